// Round 1
// baseline (1646.478 us; speedup 1.0000x reference)
//
#include <hip/hip_runtime.h>
#include <math.h>

#define BB 256
#define SS 256
#define KK 64
#define DD 128

// ---------------------------------------------------------------------------
// Precompute 1: kV[b,k,e] = sum_d keys[b,k,d] * V[d,e]
// ---------------------------------------------------------------------------
__global__ __launch_bounds__(256) void kv_kernel(const float* __restrict__ keys,
                                                 const float* __restrict__ V,
                                                 float* __restrict__ kV)
{
    __shared__ __align__(16) float Ks[KK][DD];   // 32 KB
    __shared__ __align__(16) float Vs[DD][DD];   // 64 KB
    const int b = blockIdx.x;
    const int t = threadIdx.x;
    const float* kb = keys + (size_t)b * KK * DD;
    for (int i = t; i < KK * DD / 4; i += 256) ((float4*)Ks)[i] = ((const float4*)kb)[i];
    for (int i = t; i < DD * DD / 4; i += 256) ((float4*)Vs)[i] = ((const float4*)V)[i];
    __syncthreads();

    const int e0 = (t & 15) * 8;
    const int k0 = (t >> 4) * 4;
    float acc[4][8];
#pragma unroll
    for (int i = 0; i < 4; ++i)
#pragma unroll
        for (int j = 0; j < 8; ++j) acc[i][j] = 0.f;

#pragma unroll 4
    for (int d = 0; d < DD; ++d) {
        float a0 = Ks[k0 + 0][d], a1 = Ks[k0 + 1][d], a2 = Ks[k0 + 2][d], a3 = Ks[k0 + 3][d];
        float4 v0 = *(const float4*)&Vs[d][e0];
        float4 v1 = *(const float4*)&Vs[d][e0 + 4];
        float aa[4] = {a0, a1, a2, a3};
        float vv[8] = {v0.x, v0.y, v0.z, v0.w, v1.x, v1.y, v1.z, v1.w};
#pragma unroll
        for (int i = 0; i < 4; ++i)
#pragma unroll
            for (int j = 0; j < 8; ++j) acc[i][j] = fmaf(aa[i], vv[j], acc[i][j]);
    }
    float* o = kV + (size_t)b * KK * DD;
#pragma unroll
    for (int i = 0; i < 4; ++i)
#pragma unroll
        for (int j = 0; j < 8; j += 4) {
            float4 w4 = {acc[i][j], acc[i][j + 1], acc[i][j + 2], acc[i][j + 3]};
            *(float4*)&o[(k0 + i) * DD + e0 + j] = w4;
        }
}

// ---------------------------------------------------------------------------
// Precompute 2: sW[b,t,e] = sum_d enc[b,t,d] * W[d,e]   (tile of 64 t-rows)
// ---------------------------------------------------------------------------
__global__ __launch_bounds__(256) void sw_kernel(const float* __restrict__ enc,
                                                 const float* __restrict__ W,
                                                 float* __restrict__ sW)
{
    __shared__ __align__(16) float Es[64][DD];   // 32 KB
    __shared__ __align__(16) float Ws[DD][DD];   // 64 KB
    const int blk = blockIdx.x;
    const int b = blk >> 2;
    const int tt = blk & 3;
    const int t = threadIdx.x;
    const float* eb = enc + ((size_t)b * SS + tt * 64) * DD;
    for (int i = t; i < 64 * DD / 4; i += 256) ((float4*)Es)[i] = ((const float4*)eb)[i];
    for (int i = t; i < DD * DD / 4; i += 256) ((float4*)Ws)[i] = ((const float4*)W)[i];
    __syncthreads();

    const int e0 = (t & 15) * 8;
    const int r0 = (t >> 4) * 4;
    float acc[4][8];
#pragma unroll
    for (int i = 0; i < 4; ++i)
#pragma unroll
        for (int j = 0; j < 8; ++j) acc[i][j] = 0.f;

#pragma unroll 4
    for (int d = 0; d < DD; ++d) {
        float a0 = Es[r0 + 0][d], a1 = Es[r0 + 1][d], a2 = Es[r0 + 2][d], a3 = Es[r0 + 3][d];
        float4 v0 = *(const float4*)&Ws[d][e0];
        float4 v1 = *(const float4*)&Ws[d][e0 + 4];
        float aa[4] = {a0, a1, a2, a3};
        float vv[8] = {v0.x, v0.y, v0.z, v0.w, v1.x, v1.y, v1.z, v1.w};
#pragma unroll
        for (int i = 0; i < 4; ++i)
#pragma unroll
            for (int j = 0; j < 8; ++j) acc[i][j] = fmaf(aa[i], vv[j], acc[i][j]);
    }
    float* o = sW + ((size_t)b * SS + tt * 64) * DD;
#pragma unroll
    for (int i = 0; i < 4; ++i)
#pragma unroll
        for (int j = 0; j < 8; j += 4) {
            float4 w4 = {acc[i][j], acc[i][j + 1], acc[i][j + 2], acc[i][j + 3]};
            *(float4*)&o[(r0 + i) * DD + e0 + j] = w4;
        }
}

// ---------------------------------------------------------------------------
// Precompute 3: sk[b,t,k] = sum_d enc[b,t,d] * keys[b,k,d]
// ---------------------------------------------------------------------------
__global__ __launch_bounds__(256) void sk_kernel(const float* __restrict__ enc,
                                                 const float* __restrict__ keys,
                                                 float* __restrict__ sk)
{
    __shared__ __align__(16) float Es[64][DD];   // 32 KB
    __shared__ __align__(16) float Ks[KK][DD];   // 32 KB
    const int blk = blockIdx.x;
    const int b = blk >> 2;
    const int tt = blk & 3;
    const int t = threadIdx.x;
    const float* eb = enc + ((size_t)b * SS + tt * 64) * DD;
    const float* kb = keys + (size_t)b * KK * DD;
    for (int i = t; i < 64 * DD / 4; i += 256) ((float4*)Es)[i] = ((const float4*)eb)[i];
    for (int i = t; i < KK * DD / 4; i += 256) ((float4*)Ks)[i] = ((const float4*)kb)[i];
    __syncthreads();

    const int r0 = (t >> 4) * 4;   // 16 row-tiles * 4 = 64 rows
    const int k0 = (t & 15) * 4;   // 16 key-tiles * 4 = 64 keys
    float acc[4][4];
#pragma unroll
    for (int i = 0; i < 4; ++i)
#pragma unroll
        for (int j = 0; j < 4; ++j) acc[i][j] = 0.f;

#pragma unroll 4
    for (int d = 0; d < DD; ++d) {
        float er[4], kr[4];
#pragma unroll
        for (int i = 0; i < 4; ++i) er[i] = Es[r0 + i][d];
#pragma unroll
        for (int j = 0; j < 4; ++j) kr[j] = Ks[k0 + j][d];
#pragma unroll
        for (int i = 0; i < 4; ++i)
#pragma unroll
            for (int j = 0; j < 4; ++j) acc[i][j] = fmaf(er[i], kr[j], acc[i][j]);
    }
    float* o = sk + ((size_t)b * SS + tt * 64) * KK;
#pragma unroll
    for (int i = 0; i < 4; ++i) {
        float4 w4 = {acc[i][0], acc[i][1], acc[i][2], acc[i][3]};
        *(float4*)&o[(r0 + i) * KK + k0] = w4;
    }
}

// ---------------------------------------------------------------------------
// Main sequential kernel: one block per batch, S steps inside the block.
//   gate  g[k]    = sigmoid( sum_d s[d]*h[k,d] + sk[b,t,k] )
//   htil[k,e]     = relu( sum_d h[k,d]*U[d,e] + kV[b,k,e] + sW[b,t,e] )
//   upd           = l2norm( h + g*htil );  h = mask ? upd : h
// h kept transposed in LDS (hT[d][k]) for the matmul; per-thread 4k x 8e tile
// of h also lives in registers (hreg) so the epilogue never re-reads LDS h.
// ---------------------------------------------------------------------------
__global__ __launch_bounds__(256, 1) void entnet_main(
    const float* __restrict__ enc,   // [B,S,D]
    const int*   __restrict__ mask,  // [B,S]
    const float* __restrict__ U,     // [D,D]
    const float* __restrict__ sW,    // [B,S,D]
    const float* __restrict__ sk,    // [B,S,K]
    const float* __restrict__ kV,    // [B,K,D]
    float*       __restrict__ out)   // [B,K,D]
{
    __shared__ __align__(16) float hT[DD][KK];   // 32 KB, h transposed
    __shared__ __align__(16) float Us[DD][DD];   // 64 KB
    __shared__ __align__(16) float kVs[KK][DD];  // 32 KB
    __shared__ __align__(16) float s_sh[DD];
    __shared__ __align__(16) float sW_sh[DD];
    __shared__ __align__(16) float g_sh[KK];

    const int b = blockIdx.x;
    const int t = threadIdx.x;

    // stage U, kV; zero hT
    for (int i = t; i < DD * DD / 4; i += 256) ((float4*)Us)[i] = ((const float4*)U)[i];
    const float* kVb = kV + (size_t)b * KK * DD;
    for (int i = t; i < KK * DD / 4; i += 256) ((float4*)kVs)[i] = ((const float4*)kVb)[i];
    for (int i = t; i < DD * KK / 4; i += 256) ((float4*)hT)[i] = make_float4(0.f, 0.f, 0.f, 0.f);
    __syncthreads();

    const int etile = t & 15, ktile = t >> 4;
    const int e0 = etile * 8, k0 = ktile * 4;
    const int gk = t >> 2, gq = t & 3;   // gate mapping: 64 k x 4 d-quarters

    float hreg[4][8];                    // this thread's h[k0:k0+4][e0:e0+8]
#pragma unroll
    for (int i = 0; i < 4; ++i)
#pragma unroll
        for (int j = 0; j < 8; ++j) hreg[i][j] = 0.f;

    for (int step = 0; step < SS; ++step) {
        const int m = mask[b * SS + step];
        if (m == 0) continue;            // exact no-op step (block-uniform)

        const float* sp  = enc + ((size_t)b * SS + step) * DD;
        const float* swp = sW  + ((size_t)b * SS + step) * DD;
        if (t < DD) { s_sh[t] = sp[t]; sW_sh[t] = swp[t]; }
        __syncthreads();

        // ---- gate: g[gk] = sigmoid(sk + sum_d s[d]*hT[d][gk]) ----
        float part = 0.f;
#pragma unroll
        for (int i = 0; i < 32; ++i) {
            int d = (i << 2) | gq;
            part = fmaf(s_sh[d], hT[d][gk], part);
        }
        part += __shfl_xor(part, 1);
        part += __shfl_xor(part, 2);
        if (gq == 0) {
            float x = part + sk[((size_t)b * SS + step) * KK + gk];
            g_sh[gk] = 1.f / (1.f + expf(-x));
        }
        __syncthreads();

        // ---- matmul: acc[i][j] = sum_d hT[d][k0+i] * Us[d][e0+j] ----
        float acc[4][8];
#pragma unroll
        for (int i = 0; i < 4; ++i)
#pragma unroll
            for (int j = 0; j < 8; ++j) acc[i][j] = 0.f;

#pragma unroll 4
        for (int d = 0; d < DD; ++d) {
            float4 hv = *(const float4*)&hT[d][k0];
            float4 u0 = *(const float4*)&Us[d][e0];
            float4 u1 = *(const float4*)&Us[d][e0 + 4];
            float hh[4] = {hv.x, hv.y, hv.z, hv.w};
            float uu[8] = {u0.x, u0.y, u0.z, u0.w, u1.x, u1.y, u1.z, u1.w};
#pragma unroll
            for (int i = 0; i < 4; ++i)
#pragma unroll
                for (int j = 0; j < 8; ++j) acc[i][j] = fmaf(hh[i], uu[j], acc[i][j]);
        }

        // ---- epilogue: relu, gate, l2-normalize ----
        float g4[4];
#pragma unroll
        for (int i = 0; i < 4; ++i) g4[i] = g_sh[k0 + i];
        float sw8[8];
#pragma unroll
        for (int j = 0; j < 8; ++j) sw8[j] = sW_sh[e0 + j];

        float upd[4][8], ss[4];
#pragma unroll
        for (int i = 0; i < 4; ++i) {
            float4 kv0 = *(const float4*)&kVs[k0 + i][e0];
            float4 kv1 = *(const float4*)&kVs[k0 + i][e0 + 4];
            float kv[8] = {kv0.x, kv0.y, kv0.z, kv0.w, kv1.x, kv1.y, kv1.z, kv1.w};
            float si = 0.f;
#pragma unroll
            for (int j = 0; j < 8; ++j) {
                float ht = fmaxf(acc[i][j] + kv[j] + sw8[j], 0.f);
                float u  = fmaf(g4[i], ht, hreg[i][j]);
                upd[i][j] = u;
                si = fmaf(u, u, si);
            }
            ss[i] = si;
        }
        // reduce sumsq across the 16 e-tile lanes (contiguous lanes, same wave)
#pragma unroll
        for (int w = 1; w < 16; w <<= 1) {
#pragma unroll
            for (int i = 0; i < 4; ++i) ss[i] += __shfl_xor(ss[i], w);
        }
        float rinv[4];
#pragma unroll
        for (int i = 0; i < 4; ++i) rinv[i] = 1.f / sqrtf(fmaxf(ss[i], 1e-12f));
#pragma unroll
        for (int i = 0; i < 4; ++i)
#pragma unroll
            for (int j = 0; j < 8; ++j) hreg[i][j] = upd[i][j] * rinv[i];

        __syncthreads();   // all hT reads done before overwrite
        // write back hT[e0+j][k0:k0+4]
#pragma unroll
        for (int j = 0; j < 8; ++j) {
            float4 wv = {hreg[0][j], hreg[1][j], hreg[2][j], hreg[3][j]};
            *(float4*)&hT[e0 + j][k0] = wv;
        }
        __syncthreads();
    }

    // final h -> out, coalesced from registers
    float* ob = out + (size_t)b * KK * DD;
#pragma unroll
    for (int i = 0; i < 4; ++i)
#pragma unroll
        for (int j = 0; j < 8; j += 4) {
            float4 w4 = {hreg[i][j], hreg[i][j + 1], hreg[i][j + 2], hreg[i][j + 3]};
            *(float4*)&ob[(k0 + i) * DD + e0 + j] = w4;
        }
}

// ---------------------------------------------------------------------------
extern "C" void kernel_launch(void* const* d_in, const int* in_sizes, int n_in,
                              void* d_out, int out_size, void* d_ws, size_t ws_size,
                              hipStream_t stream)
{
    const float* enc  = (const float*)d_in[0];  // [B,S,D]
    const int*   mask = (const int*)  d_in[1];  // [B,S]
    const float* keys = (const float*)d_in[2];  // [B,K,D]
    const float* U    = (const float*)d_in[3];  // [D,D]
    const float* V    = (const float*)d_in[4];  // [D,D]
    const float* W    = (const float*)d_in[5];  // [D,D]
    float* out = (float*)d_out;

    // workspace layout: sW [B,S,D] | sk [B,S,K] | kV [B,K,D]   (56 MB total)
    float* sW = (float*)d_ws;
    float* sk = sW + (size_t)BB * SS * DD;
    float* kV = sk + (size_t)BB * SS * KK;

    kv_kernel<<<BB, 256, 0, stream>>>(keys, V, kV);
    sw_kernel<<<BB * 4, 256, 0, stream>>>(enc, W, sW);
    sk_kernel<<<BB * 4, 256, 0, stream>>>(enc, keys, sk);
    entnet_main<<<BB, 256, 0, stream>>>(enc, mask, U, sW, sk, kV, out);
}

// Round 2
// 494.309 us; speedup vs baseline: 3.3309x; 3.3309x over previous
//
#include <hip/hip_runtime.h>
#include <math.h>

#define BB 256
#define SS 256
#define KK 64
#define DD 128

typedef short bf16x8 __attribute__((ext_vector_type(8)));
typedef float f32x4 __attribute__((ext_vector_type(4)));

__device__ __forceinline__ unsigned short bf16_rne(float x) {
  unsigned u = __float_as_uint(x);
  unsigned r = ((u >> 16) & 1u) + 0x7fffu;
  return (unsigned short)((u + r) >> 16);
}

// ---------------------------------------------------------------------------
// Precompute 1: kV[b,k,e] = sum_d keys[b,k,d] * V[d,e]   (fp32, proven)
// ---------------------------------------------------------------------------
__global__ __launch_bounds__(256) void kv_kernel(const float* __restrict__ keys,
                                                 const float* __restrict__ V,
                                                 float* __restrict__ kV)
{
    __shared__ __align__(16) float Ks[KK][DD];
    __shared__ __align__(16) float Vs[DD][DD];
    const int b = blockIdx.x;
    const int t = threadIdx.x;
    const float* kb = keys + (size_t)b * KK * DD;
    for (int i = t; i < KK * DD / 4; i += 256) ((float4*)Ks)[i] = ((const float4*)kb)[i];
    for (int i = t; i < DD * DD / 4; i += 256) ((float4*)Vs)[i] = ((const float4*)V)[i];
    __syncthreads();

    const int e0 = (t & 15) * 8;
    const int k0 = (t >> 4) * 4;
    float acc[4][8];
#pragma unroll
    for (int i = 0; i < 4; ++i)
#pragma unroll
        for (int j = 0; j < 8; ++j) acc[i][j] = 0.f;

#pragma unroll 4
    for (int d = 0; d < DD; ++d) {
        float aa[4] = {Ks[k0 + 0][d], Ks[k0 + 1][d], Ks[k0 + 2][d], Ks[k0 + 3][d]};
        float4 v0 = *(const float4*)&Vs[d][e0];
        float4 v1 = *(const float4*)&Vs[d][e0 + 4];
        float vv[8] = {v0.x, v0.y, v0.z, v0.w, v1.x, v1.y, v1.z, v1.w};
#pragma unroll
        for (int i = 0; i < 4; ++i)
#pragma unroll
            for (int j = 0; j < 8; ++j) acc[i][j] = fmaf(aa[i], vv[j], acc[i][j]);
    }
    float* o = kV + (size_t)b * KK * DD;
#pragma unroll
    for (int i = 0; i < 4; ++i)
#pragma unroll
        for (int j = 0; j < 8; j += 4) {
            float4 w4 = {acc[i][j], acc[i][j + 1], acc[i][j + 2], acc[i][j + 3]};
            *(float4*)&o[(k0 + i) * DD + e0 + j] = w4;
        }
}

// ---------------------------------------------------------------------------
// Precompute 2: sW[b,t,e] = sum_d enc[b,t,d] * W[d,e]
// ---------------------------------------------------------------------------
__global__ __launch_bounds__(256) void sw_kernel(const float* __restrict__ enc,
                                                 const float* __restrict__ W,
                                                 float* __restrict__ sW)
{
    __shared__ __align__(16) float Es[64][DD];
    __shared__ __align__(16) float Ws[DD][DD];
    const int blk = blockIdx.x;
    const int b = blk >> 2;
    const int tt = blk & 3;
    const int t = threadIdx.x;
    const float* eb = enc + ((size_t)b * SS + tt * 64) * DD;
    for (int i = t; i < 64 * DD / 4; i += 256) ((float4*)Es)[i] = ((const float4*)eb)[i];
    for (int i = t; i < DD * DD / 4; i += 256) ((float4*)Ws)[i] = ((const float4*)W)[i];
    __syncthreads();

    const int e0 = (t & 15) * 8;
    const int r0 = (t >> 4) * 4;
    float acc[4][8];
#pragma unroll
    for (int i = 0; i < 4; ++i)
#pragma unroll
        for (int j = 0; j < 8; ++j) acc[i][j] = 0.f;

#pragma unroll 4
    for (int d = 0; d < DD; ++d) {
        float aa[4] = {Es[r0 + 0][d], Es[r0 + 1][d], Es[r0 + 2][d], Es[r0 + 3][d]};
        float4 v0 = *(const float4*)&Ws[d][e0];
        float4 v1 = *(const float4*)&Ws[d][e0 + 4];
        float vv[8] = {v0.x, v0.y, v0.z, v0.w, v1.x, v1.y, v1.z, v1.w};
#pragma unroll
        for (int i = 0; i < 4; ++i)
#pragma unroll
            for (int j = 0; j < 8; ++j) acc[i][j] = fmaf(aa[i], vv[j], acc[i][j]);
    }
    float* o = sW + ((size_t)b * SS + tt * 64) * DD;
#pragma unroll
    for (int i = 0; i < 4; ++i)
#pragma unroll
        for (int j = 0; j < 8; j += 4) {
            float4 w4 = {acc[i][j], acc[i][j + 1], acc[i][j + 2], acc[i][j + 3]};
            *(float4*)&o[(r0 + i) * DD + e0 + j] = w4;
        }
}

// ---------------------------------------------------------------------------
// Precompute 3: sk[b,t,k] = sum_d enc[b,t,d] * keys[b,k,d]
// ---------------------------------------------------------------------------
__global__ __launch_bounds__(256) void sk_kernel(const float* __restrict__ enc,
                                                 const float* __restrict__ keys,
                                                 float* __restrict__ sk)
{
    __shared__ __align__(16) float Es[64][DD];
    __shared__ __align__(16) float Ks[KK][DD];
    const int blk = blockIdx.x;
    const int b = blk >> 2;
    const int tt = blk & 3;
    const int t = threadIdx.x;
    const float* eb = enc + ((size_t)b * SS + tt * 64) * DD;
    const float* kb = keys + (size_t)b * KK * DD;
    for (int i = t; i < 64 * DD / 4; i += 256) ((float4*)Es)[i] = ((const float4*)eb)[i];
    for (int i = t; i < KK * DD / 4; i += 256) ((float4*)Ks)[i] = ((const float4*)kb)[i];
    __syncthreads();

    const int r0 = (t >> 4) * 4;
    const int k0 = (t & 15) * 4;
    float acc[4][4];
#pragma unroll
    for (int i = 0; i < 4; ++i)
#pragma unroll
        for (int j = 0; j < 4; ++j) acc[i][j] = 0.f;

#pragma unroll 4
    for (int d = 0; d < DD; ++d) {
        float er[4], kr[4];
#pragma unroll
        for (int i = 0; i < 4; ++i) er[i] = Es[r0 + i][d];
#pragma unroll
        for (int j = 0; j < 4; ++j) kr[j] = Ks[k0 + j][d];
#pragma unroll
        for (int i = 0; i < 4; ++i)
#pragma unroll
            for (int j = 0; j < 4; ++j) acc[i][j] = fmaf(er[i], kr[j], acc[i][j]);
    }
    float* o = sk + ((size_t)b * SS + tt * 64) * KK;
#pragma unroll
    for (int i = 0; i < 4; ++i) {
        float4 w4 = {acc[i][0], acc[i][1], acc[i][2], acc[i][3]};
        *(float4*)&o[(r0 + i) * KK + k0] = w4;
    }
}

// ---------------------------------------------------------------------------
// Precompute 4: U in MFMA B-fragment order, split bf16 hi/lo.
// Ufh/Ufl layout: [ntg(8)][kt(4)][lane(64)][j(8)] bf16, value =
//   U[32*kt + 8*(lane>>4) + j][16*ntg + (lane&15)]
// ---------------------------------------------------------------------------
__global__ void ufrag_kernel(const float* __restrict__ U,
                             unsigned short* __restrict__ Ufh,
                             unsigned short* __restrict__ Ufl)
{
    const int blk = blockIdx.x;       // 32 = ntg*4 + kt
    const int ntg = blk >> 2, kt = blk & 3;
    const int l = threadIdx.x;        // 64
    const int e = ntg * 16 + (l & 15);
    const int d0 = kt * 32 + (l >> 4) * 8;
#pragma unroll
    for (int j = 0; j < 8; ++j) {
        float x = U[(d0 + j) * DD + e];
        unsigned short hi = bf16_rne(x);
        float rem = x - __uint_as_float(((unsigned)hi) << 16);
        unsigned short lo = bf16_rne(rem);
        int idx = (blk * 64 + l) * 8 + j;
        Ufh[idx] = hi;
        Ufl[idx] = lo;
    }
}

// ---------------------------------------------------------------------------
// Main sequential kernel (MFMA, split bf16). 512 threads = 8 waves.
// wave w: mt = w&3 (rows 16*mt..+15), eh = w>>2 (cols 64*eh..+63).
// h fp32 persistent in registers (D-frag layout); bf16 hi/lo copy in LDS
// in A-fragment-linear layout for next step's MFMA A operand.
// Per step: [B1] A-frag reads + 48 MFMA (waves eh==0: +12 gate MFMA),
// gate sigmoid write [B2] epilogue relu/gate/sumsq + rowsq write [B3]
// rsqrt scale, split-write hA, stage next row [B1] ...
// ---------------------------------------------------------------------------
__global__ __launch_bounds__(512, 2) void entnet_main(
    const float* __restrict__ enc,   // [B,S,D]
    const int*   __restrict__ mask,  // [B,S]
    const float* __restrict__ sWg,   // [B,S,D]
    const float* __restrict__ skg,   // [B,S,K]
    const float* __restrict__ kVg,   // [B,K,D]
    const unsigned short* __restrict__ Ufh,
    const unsigned short* __restrict__ Ufl,
    float*       __restrict__ out)   // [B,K,D]
{
    __shared__ __align__(16) unsigned short hAhi[4][4][64][8];  // 16 KB
    __shared__ __align__(16) unsigned short hAlo[4][4][64][8];  // 16 KB
    __shared__ __align__(16) unsigned short shi_sh[2][DD];
    __shared__ __align__(16) unsigned short slo_sh[2][DD];
    __shared__ __align__(16) float sW_sh[2][DD];
    __shared__ __align__(16) float sk_sh[2][KK];
    __shared__ float g_sh[KK];
    __shared__ float rowsq_sh[2][KK];
    __shared__ int act_sh[SS];
    __shared__ int m_sh[SS];
    __shared__ int nact_sh;

    const int b = blockIdx.x;
    const int t = threadIdx.x;
    const int w = t >> 6, l = t & 63;
    const int mt = w & 3, eh = w >> 2;
    const int gi = l >> 4, li = l & 15;
    const int slot_r = l ^ ((l >> 2) & 3);
    const int role = t >> 7;          // 0: s-row, 1: sW-row, 2: sk-row (t<320)

    // ---- stage mask, zero hA ----
    if (t < SS) m_sh[t] = mask[b * SS + t];
    {
        unsigned int* p = (unsigned int*)&hAhi[0][0][0][0];
        unsigned int* q = (unsigned int*)&hAlo[0][0][0][0];
        for (int i = t; i < 4 * 4 * 64 * 8 / 2; i += 512) { p[i] = 0u; q[i] = 0u; }
    }
    __syncthreads();
    if (t == 0) {
        int c = 0;
        for (int i = 0; i < SS; ++i) if (m_sh[i]) act_sh[c++] = i;
        nact_sh = c;
    }

    // ---- U fragments (regs), kV (regs), h=0 ----
    bf16x8 ufh[4][4], ufl[4][4];
#pragma unroll
    for (int nt = 0; nt < 4; ++nt)
#pragma unroll
        for (int kt = 0; kt < 4; ++kt) {
            int ntg = eh * 4 + nt;
            int off = ((ntg * 4 + kt) * 64 + l) * 8;
            ufh[nt][kt] = *(const bf16x8*)&Ufh[off];
            ufl[nt][kt] = *(const bf16x8*)&Ufl[off];
        }
    float kvreg[4][4];
#pragma unroll
    for (int nt = 0; nt < 4; ++nt)
#pragma unroll
        for (int reg = 0; reg < 4; ++reg) {
            int k = 16 * mt + 4 * gi + reg;
            int e = 64 * eh + 16 * nt + li;
            kvreg[nt][reg] = kVg[((size_t)b * KK + k) * DD + e];
        }
    f32x4 hreg[4];
#pragma unroll
    for (int nt = 0; nt < 4; ++nt) hreg[nt] = (f32x4){0.f, 0.f, 0.f, 0.f};
    __syncthreads();

    const int nact = nact_sh;
    // ---- prologue: stage rows for act[0] into buffer 0 ----
    if (nact > 0 && t < 320) {
        int t0i = act_sh[0];
        if (role == 0) {
            float x = enc[((size_t)b * SS + t0i) * DD + t];
            unsigned u = __float_as_uint(x);
            shi_sh[0][t] = (unsigned short)(u >> 16);
            float rem = x - __uint_as_float(u & 0xffff0000u);
            slo_sh[0][t] = (unsigned short)(__float_as_uint(rem) >> 16);
        } else if (role == 1) {
            sW_sh[0][t - 128] = sWg[((size_t)b * SS + t0i) * DD + (t - 128)];
        } else {
            sk_sh[0][t - 256] = skg[((size_t)b * SS + t0i) * KK + (t - 256)];
        }
    }
    __syncthreads();

    for (int ai = 0; ai < nact; ++ai) {
        const int cur = ai & 1, nxt = cur ^ 1;
        // prefetch next active row into regs (consumed after B3)
        float pf = 0.f;
        const bool have = (ai + 1 < nact);
        if (have && t < 320) {
            int tn = act_sh[ai + 1];
            if (role == 0)      pf = enc[((size_t)b * SS + tn) * DD + t];
            else if (role == 1) pf = sWg[((size_t)b * SS + tn) * DD + (t - 128)];
            else                pf = skg[((size_t)b * SS + tn) * KK + (t - 256)];
        }

        // ---- MFMA phase: acc = h@U (3-term split), gacc = h.s ----
        f32x4 acc[4];
#pragma unroll
        for (int nt = 0; nt < 4; ++nt) acc[nt] = (f32x4){0.f, 0.f, 0.f, 0.f};
        f32x4 gacc = (f32x4){0.f, 0.f, 0.f, 0.f};
#pragma unroll
        for (int kt = 0; kt < 4; ++kt) {
            bf16x8 ah = *(const bf16x8*)&hAhi[kt][mt][slot_r][0];
            bf16x8 al = *(const bf16x8*)&hAlo[kt][mt][slot_r][0];
#pragma unroll
            for (int nt = 0; nt < 4; ++nt) {
                acc[nt] = __builtin_amdgcn_mfma_f32_16x16x32_bf16(ah, ufh[nt][kt], acc[nt], 0, 0, 0);
                acc[nt] = __builtin_amdgcn_mfma_f32_16x16x32_bf16(al, ufh[nt][kt], acc[nt], 0, 0, 0);
                acc[nt] = __builtin_amdgcn_mfma_f32_16x16x32_bf16(ah, ufl[nt][kt], acc[nt], 0, 0, 0);
            }
            if (eh == 0) {
                bf16x8 sh = *(const bf16x8*)&shi_sh[cur][32 * kt + 8 * gi];
                bf16x8 sl = *(const bf16x8*)&slo_sh[cur][32 * kt + 8 * gi];
                gacc = __builtin_amdgcn_mfma_f32_16x16x32_bf16(ah, sh, gacc, 0, 0, 0);
                gacc = __builtin_amdgcn_mfma_f32_16x16x32_bf16(al, sh, gacc, 0, 0, 0);
                gacc = __builtin_amdgcn_mfma_f32_16x16x32_bf16(ah, sl, gacc, 0, 0, 0);
            }
        }
        if (eh == 0 && li == 0) {
#pragma unroll
            for (int reg = 0; reg < 4; ++reg) {
                int k = 16 * mt + 4 * gi + reg;
                float x = gacc[reg] + sk_sh[cur][k];
                g_sh[k] = 1.f / (1.f + __expf(-x));
            }
        }
        __syncthreads();  // B2: g ready; all hA / s reads done

        // ---- epilogue part 1: upd = h + g*relu(acc+kV+sW), row sumsq ----
        float g4[4], sw4[4];
#pragma unroll
        for (int reg = 0; reg < 4; ++reg) g4[reg] = g_sh[16 * mt + 4 * gi + reg];
#pragma unroll
        for (int nt = 0; nt < 4; ++nt) sw4[nt] = sW_sh[cur][64 * eh + 16 * nt + li];
        f32x4 upd[4];
        float ss[4] = {0.f, 0.f, 0.f, 0.f};
#pragma unroll
        for (int nt = 0; nt < 4; ++nt)
#pragma unroll
            for (int reg = 0; reg < 4; ++reg) {
                float v = acc[nt][reg] + kvreg[nt][reg] + sw4[nt];
                v = fmaxf(v, 0.f);
                float u = fmaf(g4[reg], v, hreg[nt][reg]);
                upd[nt][reg] = u;
                ss[reg] = fmaf(u, u, ss[reg]);
            }
#pragma unroll
        for (int m = 1; m < 16; m <<= 1)
#pragma unroll
            for (int reg = 0; reg < 4; ++reg) ss[reg] += __shfl_xor(ss[reg], m);
        if (li == 0) {
#pragma unroll
            for (int reg = 0; reg < 4; ++reg)
                rowsq_sh[eh][16 * mt + 4 * gi + reg] = ss[reg];
        }
        __syncthreads();  // B3: both half sums ready

        float rinv[4];
#pragma unroll
        for (int reg = 0; reg < 4; ++reg) {
            float tot = ss[reg] + rowsq_sh[1 - eh][16 * mt + 4 * gi + reg];
            rinv[reg] = rsqrtf(fmaxf(tot, 1e-12f));
        }
        // ---- normalize, split bf16, store into hA (A-frag-linear, swizzled) ----
#pragma unroll
        for (int nt = 0; nt < 4; ++nt) {
            int kt_w = 2 * eh + (nt >> 1);
            int b23  = (2 * nt + (li >> 3)) & 3;
            int j    = l & 7;
#pragma unroll
            for (int reg = 0; reg < 4; ++reg) {
                float hn = upd[nt][reg] * rinv[reg];
                hreg[nt][reg] = hn;
                unsigned u = __float_as_uint(hn);
                unsigned short hi = (unsigned short)(u >> 16);
                float rem = hn - __uint_as_float(u & 0xffff0000u);
                unsigned short lo = (unsigned short)(__float_as_uint(rem) >> 16);
                int le = (4 * gi + reg) | (b23 << 4);
                int slot_w = le ^ ((le >> 2) & 3);
                hAhi[kt_w][mt][slot_w][j] = hi;
                hAlo[kt_w][mt][slot_w][j] = lo;
            }
        }
        // ---- stage next row into buffer nxt ----
        if (have && t < 320) {
            if (role == 0) {
                unsigned u = __float_as_uint(pf);
                shi_sh[nxt][t] = (unsigned short)(u >> 16);
                float rem = pf - __uint_as_float(u & 0xffff0000u);
                slo_sh[nxt][t] = (unsigned short)(__float_as_uint(rem) >> 16);
            } else if (role == 1) sW_sh[nxt][t - 128] = pf;
            else                  sk_sh[nxt][t - 256] = pf;
        }
        __syncthreads();  // B1: hA + staged rows visible for next iter
    }

    // ---- final h -> out ----
#pragma unroll
    for (int nt = 0; nt < 4; ++nt)
#pragma unroll
        for (int reg = 0; reg < 4; ++reg) {
            int k = 16 * mt + 4 * gi + reg;
            int e = 64 * eh + 16 * nt + li;
            out[((size_t)b * KK + k) * DD + e] = hreg[nt][reg];
        }
}

// ---------------------------------------------------------------------------
extern "C" void kernel_launch(void* const* d_in, const int* in_sizes, int n_in,
                              void* d_out, int out_size, void* d_ws, size_t ws_size,
                              hipStream_t stream)
{
    const float* enc  = (const float*)d_in[0];  // [B,S,D]
    const int*   mask = (const int*)  d_in[1];  // [B,S]
    const float* keys = (const float*)d_in[2];  // [B,K,D]
    const float* U    = (const float*)d_in[3];  // [D,D]
    const float* V    = (const float*)d_in[4];  // [D,D]
    const float* W    = (const float*)d_in[5];  // [D,D]
    float* out = (float*)d_out;

    // ws layout: sW [B,S,D] | sk [B,S,K] | kV [B,K,D] | Ufh | Ufl
    float* sW = (float*)d_ws;
    float* sk = sW + (size_t)BB * SS * DD;
    float* kV = sk + (size_t)BB * SS * KK;
    unsigned short* Ufh = (unsigned short*)(kV + (size_t)BB * KK * DD);
    unsigned short* Ufl = Ufh + 8 * 4 * 64 * 8;

    kv_kernel<<<BB, 256, 0, stream>>>(keys, V, kV);
    sw_kernel<<<BB * 4, 256, 0, stream>>>(enc, W, sW);
    sk_kernel<<<BB * 4, 256, 0, stream>>>(enc, keys, sk);
    ufrag_kernel<<<32, 64, 0, stream>>>(U, Ufh, Ufl);
    entnet_main<<<BB, 512, 0, stream>>>(enc, mask, sW, sk, kV, Ufh, Ufl, out);
}